// Round 5
// baseline (335.999 us; speedup 1.0000x reference)
//
#include <hip/hip_runtime.h>

#define SS 1024
#define BB 128
#define HH 1024
#define DD 2048
#define NROWS (SS*BB)            // 131072 (t,b) rows
#define NSEG 16
#define TSEG 64                  // segment = 64 timesteps (cacheline-aligned in pre)
#define ROWSEG (TSEG*BB)         // 8192 rows per segment
#define NSCANB 4                 // blocks 0..3 -> 16 scan waves
#define NK1B   512               // 2048 k1 waves (read x -> pre), seg-ordered
#define NK3B   504               // 2016 k3 waves (s_out -> out broadcast)
#define NBLK   (NSCANB+NK1B+NK3B)  // 1020 blocks <= 4/CU x 256CU -> co-resident
#define K1WAVES 2048
#define L2E  1.4426950408889634f
#define PF 16

// flags layout (ints, 128B-strided to avoid same-line RMW contention):
//   k1done shard: flags[(seg*8+shard)*32], target 256 each (8 shards = 2048 waves)
//   scandone:     flags[4096 + seg*32],    target 16
#define K1FLAG(s,sh) (((s)*8 + (sh))*32)
#define SCFLAG(s)    (4096 + (s)*32)
#define FLAG_INTS    4608

typedef float f32x4 __attribute__((ext_vector_type(4)));

__device__ __forceinline__ float fast_rcp(float x)  { return __builtin_amdgcn_rcpf(x); }
__device__ __forceinline__ float exp2_(float x)     { return __builtin_amdgcn_exp2f(x); }

// R16: cross-wave payloads MUST use device-coherent ops. NT stores are only
// an evict hint: they sit dirty in the writer XCD's L2; readers on other
// XCDs fetch stale lines from IC (R15's absmax 2e-2 / 488 failure). Using
// __hip_atomic_* AGENT-scope relaxed makes the compiler emit sc1
// write-through stores / L2-bypass loads -- correctness by construction.
__device__ __forceinline__ void st_dev(float* p, float v){
    __hip_atomic_store(p, v, __ATOMIC_RELAXED, __HIP_MEMORY_SCOPE_AGENT);
}
__device__ __forceinline__ float ld_dev(const float* p){
    return __hip_atomic_load(p, __ATOMIC_RELAXED, __HIP_MEMORY_SCOPE_AGENT);
}

template<int CTRL>
__device__ __forceinline__ float qperm(float x){
    return __int_as_float(__builtin_amdgcn_update_dpp(0, __float_as_int(x), CTRL, 0xF, 0xF, true));
}
__device__ __forceinline__ float rowshr4(float x){
    return __int_as_float(__builtin_amdgcn_update_dpp(0, __float_as_int(x), 0x114, 0xF, 0xF, true));
}

// Single persistent dataflow kernel (R15 architecture, R16 coherence fix).
//  - 2048 k1 waves sweep segments IN ORDER: x(NT read) -> pre(agent store)
//  - 16 scan waves chase k1 via sharded flags; pre(agent load) ->
//    s_out/finals(agent store)
//  - 2016 k3 waves chase scan: s_out(agent load) -> out(NT store; no
//    in-kernel reader, kernel-end flush handles host visibility)
// Publish = s_waitcnt(0) (payload ACKed at coherence point) + relaxed
// agent atomicAdd. Consume = relaxed agent spin + compiler barrier (loads
// can't hoist above the spin; HW won't speculate past the branch).
__global__ __launch_bounds__(256, 4) void lstm_df(
    const float* __restrict__ x, const float* __restrict__ W,
    const float* __restrict__ bias, float* out,
    float* __restrict__ s_out, float* __restrict__ finals,
    int* __restrict__ flags)
{
    float* pre = out + (size_t)NROWS * HH;   // hT/cT rows (2 MB) as pre scratch
    const int tid  = threadIdx.x;
    const int lane = tid & 63;
    const int wv   = tid >> 6;
    const int blk  = blockIdx.x;

    if (blk < NSCANB) {
        // ---------------- scan wave (16 waves, 8 batches each) ----------------
        const int sw   = blk*4 + wv;          // 0..15
        const int gate = lane & 3;
        const int L    = (lane >> 2) & 1;
        const int lb   = lane >> 3;
        const int bb   = sw*8 + lb;

        // 12 weight sums computed in-register (xor-tree leaves total in all lanes)
        float sh = 0.f, sx = 0.f;
        for (int q = 0; q < 12; ++q) {
            const int base = (q < 4) ? q*DD
                           : (q < 8) ? 4*DD + (q-4)*DD
                                     : 4*DD + (q-8)*DD + HH;
            float v = 0.f;
            #pragma unroll
            for (int k = 0; k < 16; ++k) v += W[base + lane + k*64];
            #pragma unroll
            for (int off = 32; off >= 1; off >>= 1) v += __shfl_xor(v, off, 64);
            if (q == L*4 + gate) sh = v;
            if (q == 8 + gate)   sx = v;
        }
        const float sc  = (gate == 1) ? (2.0f*L2E) : (-L2E);
        const float s_h = sh * sc;
        const float sxc = L ? sx * sc : 0.0f;
        const float pcc = L ? bias[4+gate] * sc : 0.0f;
        const float Ac  = (gate == 1) ? 1.0f : 0.0f;
        const float Bc  = (gate == 0) ? (2.0f*L2E) : ((gate == 1) ? -2.0f : 1.0f);

        const float* pbase = pre + ((size_t)bb << 12) + gate;   // + t*4
        float* obase = s_out + bb;

        float h = 0.f, cp = 0.f, h0d1 = 0.f, h0d2 = 0.f;        // persistent state

        for (int s = 0; s < NSEG; ++s) {
            // wait k1(s): sum of 8 shards == 2048
            {
                int guard = 0;
                for (;;) {
                    int tot = 0;
                    #pragma unroll
                    for (int i = 0; i < 8; ++i)
                        tot += __hip_atomic_load(&flags[K1FLAG(s,i)], __ATOMIC_RELAXED, __HIP_MEMORY_SCOPE_AGENT);
                    if (tot >= K1WAVES) break;
                    __builtin_amdgcn_s_sleep(8);
                    if (++guard > (1<<20)) break;   // never hit legitimately
                }
                asm volatile("" ::: "memory");      // no payload-load hoisting
            }
            const int t_lo = s*TSEG, t_hi = t_lo + TSEG;
            float buf[PF];
            #pragma unroll
            for (int u = 0; u < PF; ++u)
                buf[u] = ld_dev(pbase + (size_t)(t_lo + u) * 4);

            for (int t0 = t_lo; t0 < t_hi; t0 += PF) {
                #pragma unroll
                for (int u = 0; u < PF; ++u) {
                    const int t = t0 + u;
                    const float p = L ? pcc : buf[u];
                    int tn = t + PF; if (tn > t_hi-1) tn = t_hi-1;   // stay in segment
                    buf[u] = ld_dev(pbase + (size_t)tn * 4);

                    const float P = fmaf(h0d2, sxc, p);      // L1 consumes h0_{t-2}
                    const float g = fmaf(h, s_h, P);
                    const float v = fmaf(Bc, fast_rcp(1.0f + exp2_(g)), Ac);
                    const float w = v * qperm<0xB1>(v);
                    const float cpn = fmaf(qperm<0xAA>(v), cp, qperm<0x00>(w));
                    const float th = fmaf(-2.0f, fast_rcp(1.0f + exp2_(cpn)), 1.0f);
                    const float hn = qperm<0xFF>(v) * th;
                    // first 2 steps of each segment: L1 redoes steps done by the
                    // previous segment's flush (or spin-up at t=0) -> discard.
                    const bool disc = (u < 2) && (t0 == t_lo) && L;
                    h  = disc ? h  : hn;
                    cp = disc ? cp : cpn;
                    h0d2 = h0d1;
                    h0d1 = rowshr4(h);                       // L0 h -> L1 quad (DPP)
                    if (L && t >= t_lo + 2)
                        st_dev(obase + (size_t)(t-2) * BB, h);
                }
            }

            const float h0f = h, c0f = cp;       // L0 finals (flush skips L0)

            // flush: 2 L1-only steps so rows [t_hi-2, t_hi) publish this segment
            #pragma unroll
            for (int fs = 0; fs < 2; ++fs) {
                const float p = L ? pcc : buf[0];
                const float P = fmaf(h0d2, sxc, p);
                const float g = fmaf(h, s_h, P);
                const float v = fmaf(Bc, fast_rcp(1.0f + exp2_(g)), Ac);
                const float w = v * qperm<0xB1>(v);
                const float cpn = fmaf(qperm<0xAA>(v), cp, qperm<0x00>(w));
                const float th = fmaf(-2.0f, fast_rcp(1.0f + exp2_(cpn)), 1.0f);
                const float hn = qperm<0xFF>(v) * th;
                if (L) { h = hn; cp = cpn;
                         st_dev(obase + (size_t)(t_hi-2+fs) * BB, hn); }
                h0d2 = h0d1;
            }

            if (s == NSEG-1 && gate == 0) {
                if (L) { st_dev(finals + 128 + bb, h);
                         st_dev(finals + 384 + bb, cp  * (0.5f/L2E)); }
                else   { st_dev(finals + bb,       h0f);
                         st_dev(finals + 256 + bb, c0f * (0.5f/L2E)); }
            }

            __builtin_amdgcn_s_waitcnt(0);       // payload stores ACKed at IC
            if (lane == 0)
                __hip_atomic_fetch_add(&flags[SCFLAG(s)], 1, __ATOMIC_RELAXED, __HIP_MEMORY_SCOPE_AGENT);
        }
        return;
    }

    if (blk < NSCANB + NK1B) {
        // ---------------- k1 wave (2048 waves, seg-ordered sweep) ----------------
        const int i = (blk - NSCANB)*4 + wv;     // 0..2047
        float4 wvv[4][4];
        #pragma unroll
        for (int j = 0; j < 4; ++j)
            #pragma unroll
            for (int it = 0; it < 4; ++it)
                wvv[j][it] = *(const float4*)(W + j*DD + HH + it*256 + lane*4);
        const float4 b0 = *(const float4*)(bias);

        for (int s = 0; s < NSEG; ++s) {
            #pragma unroll 2
            for (int j = 0; j < 4; ++j) {
                const int row = s*ROWSEG + i*4 + j;
                const float* xr = x + (size_t)row * HH;
                float a0 = 0.f, a1 = 0.f, a2 = 0.f, a3 = 0.f;
                #pragma unroll
                for (int it = 0; it < 4; ++it) {
                    f32x4 xv = __builtin_nontemporal_load((const f32x4*)xr + it*64 + lane);
                    a0 = fmaf(xv.x, wvv[0][it].x, fmaf(xv.y, wvv[0][it].y, fmaf(xv.z, wvv[0][it].z, fmaf(xv.w, wvv[0][it].w, a0))));
                    a1 = fmaf(xv.x, wvv[1][it].x, fmaf(xv.y, wvv[1][it].y, fmaf(xv.z, wvv[1][it].z, fmaf(xv.w, wvv[1][it].w, a1))));
                    a2 = fmaf(xv.x, wvv[2][it].x, fmaf(xv.y, wvv[2][it].y, fmaf(xv.z, wvv[2][it].z, fmaf(xv.w, wvv[2][it].w, a2))));
                    a3 = fmaf(xv.x, wvv[3][it].x, fmaf(xv.y, wvv[3][it].y, fmaf(xv.z, wvv[3][it].z, fmaf(xv.w, wvv[3][it].w, a3))));
                }
                #pragma unroll
                for (int off = 32; off >= 1; off >>= 1) {
                    a0 += __shfl_xor(a0, off, 64);
                    a1 += __shfl_xor(a1, off, 64);
                    a2 += __shfl_xor(a2, off, 64);
                    a3 += __shfl_xor(a3, off, 64);
                }
                if (lane == 0) {
                    const int b = row & (BB-1), t = row >> 7;
                    float* pr = pre + (((size_t)b << 10) + t) * 4;
                    st_dev(pr + 0, (a0 + b0.x) * (-L2E));
                    st_dev(pr + 1, (a1 + b0.y) * ( 2.0f * L2E));
                    st_dev(pr + 2, (a2 + b0.z) * (-L2E));
                    st_dev(pr + 3, (a3 + b0.w) * (-L2E));
                }
            }
            __builtin_amdgcn_s_waitcnt(0);       // pre stores ACKed at IC
            if (lane == 0)
                __hip_atomic_fetch_add(&flags[K1FLAG(s, i & 7)], 1, __ATOMIC_RELAXED, __HIP_MEMORY_SCOPE_AGENT);
        }
        return;
    }

    // ---------------- k3 wave (2016 waves, chase scan) ----------------
    const int u = (blk - NSCANB - NK1B)*4 + wv;  // 0..2015
    const int lbase = (u < 32) ? u*8 : 256 + (u-32)*4;  // 32*8 + 1984*4 = 8192
    const int cnt   = (u < 32) ? 8 : 4;
    for (int s = 0; s < NSEG; ++s) {
        {
            int guard = 0;
            while (__hip_atomic_load(&flags[SCFLAG(s)], __ATOMIC_RELAXED, __HIP_MEMORY_SCOPE_AGENT) < 16) {
                __builtin_amdgcn_s_sleep(32);
                if (++guard > (1<<19)) break;    // never hit legitimately
            }
            asm volatile("" ::: "memory");       // no payload-load hoisting
        }
        const int r0 = s*ROWSEG + lbase;
        for (int q = 0; q < cnt; q += 4) {
            float vb0 = ld_dev(s_out + r0 + q + 0);
            float vb1 = ld_dev(s_out + r0 + q + 1);
            float vb2 = ld_dev(s_out + r0 + q + 2);
            float vb3 = ld_dev(s_out + r0 + q + 3);
            #pragma unroll
            for (int jj = 0; jj < 4; ++jj) {
                const float vb = (jj==0) ? vb0 : (jj==1) ? vb1 : (jj==2) ? vb2 : vb3;
                const f32x4 vv = {vb, vb, vb, vb};
                f32x4* dst = (f32x4*)(out + (size_t)(r0 + q + jj) * HH);
                #pragma unroll
                for (int it = 0; it < 4; ++it)
                    __builtin_nontemporal_store(vv, dst + it*64 + lane);
            }
        }
    }
    if (u < 512) {
        // finals rows: safe to overwrite pre region (scan fully done)
        const float v = ld_dev(finals + u);
        const f32x4 vv = {v, v, v, v};
        f32x4* dst = (f32x4*)(out + (size_t)(NROWS + u) * HH);
        #pragma unroll
        for (int it = 0; it < 4; ++it)
            __builtin_nontemporal_store(vv, dst + it*64 + lane);
    }
}

extern "C" void kernel_launch(void* const* d_in, const int* in_sizes, int n_in,
                              void* d_out, int out_size, void* d_ws, size_t ws_size,
                              hipStream_t stream) {
    const float* x    = (const float*)d_in[0];   // [S,B,H]
    const float* W    = (const float*)d_in[1];   // [L,4,D]
    const float* bias = (const float*)d_in[2];   // [L,4]
    float* out = (float*)d_out;

    float* s_out  = (float*)d_ws;                // [131072]
    float* finals = s_out + NROWS;               // [512]
    int*   flags  = (int*)(finals + 512);        // [4608] ints

    hipMemsetAsync(flags, 0, FLAG_INTS * sizeof(int), stream);
    hipLaunchKernelGGL(lstm_df, dim3(NBLK), dim3(256), 0, stream,
                       x, W, bias, out, s_out, finals, flags);
}

// Round 6
// 279.343 us; speedup vs baseline: 1.2028x; 1.2028x over previous
//
#include <hip/hip_runtime.h>

#define SS 1024
#define BB 128
#define HH 1024
#define DD 2048
#define NROWS (SS*BB)            // 131072 (t,b) rows
#define NSEG 16
#define TSEG 64                  // segment = 64 timesteps
#define ROWSEG (TSEG*BB)         // 8192 rows per segment
#define NSCANB 4                 // blocks 0..3 -> 16 scan waves
#define NK1B   512               // 2048 k1 waves (read x -> pre), seg-ordered
#define NK3B   504               // 2016 k3 waves (s_out -> out broadcast)
#define NBLK   (NSCANB+NK1B+NK3B)  // 1020 blocks <= 4/CU x 256CU -> co-resident
#define K1WAVES 2048
#define L2E  1.4426950408889634f
#define PF 16

// flags layout (ints, 128B-strided):
//   k1done shard: flags[(seg*8+shard)*32], target 256 each (8 shards = 2048 waves)
//   scandone:     flags[4096 + seg*32],    target 16
#define K1FLAG(s,sh) (((s)*8 + (sh))*32)
#define SCFLAG(s)    (4096 + (s)*32)
#define FLAG_INTS    4608

typedef float f32x4 __attribute__((ext_vector_type(4)));

__device__ __forceinline__ float fast_rcp(float x)  { return __builtin_amdgcn_rcpf(x); }
__device__ __forceinline__ float exp2_(float x)     { return __builtin_amdgcn_exp2f(x); }

// R17: write-through stores WITHOUT atomic semantics. R16's agent-atomic
// loads/stores made the scan ~800cy/step (compiler serializes atomics with
// waitcnts -> IC round-trip per step; dur 336us, hbm 2.2TB/s, VALU 7%).
// sc0 sc1 on plain global stores = write-through past L2 to the device
// coherence point (same encoding agent-atomics lower to), but the compiler
// treats them as ordinary fire-and-forget stores.
__device__ __forceinline__ void st_wt(float* p, float v){
    asm volatile("global_store_dword %0, %1, off sc0 sc1" :: "v"(p), "v"(v));
}
__device__ __forceinline__ void st_wt_x4(float* p, f32x4 v){
    asm volatile("global_store_dwordx4 %0, %1, off sc0 sc1" :: "v"(p), "v"(v));
}
// Read side uses PLAIN NT loads. Safe: writers are write-through (no dirty
// L2 copy exists), kernel-start acquire invalidates L2s (same mechanism
// that made the phase pipeline correct), and every reader XCD first touches
// these lines only AFTER the flag -> no stale fill possible.

template<int CTRL>
__device__ __forceinline__ float qperm(float x){
    return __int_as_float(__builtin_amdgcn_update_dpp(0, __float_as_int(x), CTRL, 0xF, 0xF, true));
}
__device__ __forceinline__ float rowshr4(float x){
    return __int_as_float(__builtin_amdgcn_update_dpp(0, __float_as_int(x), 0x114, 0xF, 0xF, true));
}

// Single persistent dataflow kernel:
//  - 2048 k1 waves sweep segments IN ORDER: x(NT read) -> pre(st_wt_x4)
//  - 16 scan waves chase k1 via sharded flags; pre(NT load) -> s_out(st_wt)
//  - 2016 k3 waves chase scan (hierarchical poll: 1 global poller/block,
//    3 waves spin on LDS): s_out(NT load) -> out(NT store)
// Publish = s_waitcnt vmcnt(0) + relaxed agent atomicAdd (once/segment).
__global__ __launch_bounds__(256, 4) void lstm_df(
    const float* __restrict__ x, const float* __restrict__ W,
    const float* __restrict__ bias, float* out,
    float* __restrict__ s_out, float* __restrict__ finals,
    int* __restrict__ flags)
{
    __shared__ int ready;                    // k3 blocks: highest segment+1 ready
    float* pre = out + (size_t)NROWS * HH;   // hT/cT rows (2 MB) as pre scratch
    const int tid  = threadIdx.x;
    const int lane = tid & 63;
    const int wv   = tid >> 6;
    const int blk  = blockIdx.x;

    if (blk < NSCANB) {
        // ---------------- scan wave (16 waves, 8 batches each) ----------------
        const int sw   = blk*4 + wv;          // 0..15
        const int gate = lane & 3;
        const int L    = (lane >> 2) & 1;
        const int lb   = lane >> 3;
        const int bb   = sw*8 + lb;

        // 12 weight sums computed in-register
        float sh = 0.f, sx = 0.f;
        for (int q = 0; q < 12; ++q) {
            const int base = (q < 4) ? q*DD
                           : (q < 8) ? 4*DD + (q-4)*DD
                                     : 4*DD + (q-8)*DD + HH;
            float v = 0.f;
            #pragma unroll
            for (int k = 0; k < 16; ++k) v += W[base + lane + k*64];
            #pragma unroll
            for (int off = 32; off >= 1; off >>= 1) v += __shfl_xor(v, off, 64);
            if (q == L*4 + gate) sh = v;
            if (q == 8 + gate)   sx = v;
        }
        const float sc  = (gate == 1) ? (2.0f*L2E) : (-L2E);
        const float s_h = sh * sc;
        const float sxc = L ? sx * sc : 0.0f;
        const float pcc = L ? bias[4+gate] * sc : 0.0f;
        const float Ac  = (gate == 1) ? 1.0f : 0.0f;
        const float Bc  = (gate == 0) ? (2.0f*L2E) : ((gate == 1) ? -2.0f : 1.0f);

        const float* pbase = pre + ((size_t)bb << 12) + gate;   // + t*4
        float* obase = s_out + bb;

        float h = 0.f, cp = 0.f, h0d1 = 0.f, h0d2 = 0.f;        // persistent state

        for (int s = 0; s < NSEG; ++s) {
            // wait k1(s): sum of 8 shards == 2048
            {
                int guard = 0;
                for (;;) {
                    int tot = 0;
                    #pragma unroll
                    for (int i = 0; i < 8; ++i)
                        tot += __hip_atomic_load(&flags[K1FLAG(s,i)], __ATOMIC_RELAXED, __HIP_MEMORY_SCOPE_AGENT);
                    if (tot >= K1WAVES) break;
                    __builtin_amdgcn_s_sleep(8);
                    if (++guard > (1<<20)) break;   // never hit legitimately
                }
                asm volatile("" ::: "memory");      // no payload-load hoisting
            }
            const int t_lo = s*TSEG, t_hi = t_lo + TSEG;
            float buf[PF];
            #pragma unroll
            for (int u = 0; u < PF; ++u)
                buf[u] = __builtin_nontemporal_load(pbase + (size_t)(t_lo + u) * 4);

            for (int t0 = t_lo; t0 < t_hi; t0 += PF) {
                #pragma unroll
                for (int u = 0; u < PF; ++u) {
                    const int t = t0 + u;
                    const float p = L ? pcc : buf[u];
                    int tn = t + PF; if (tn > t_hi-1) tn = t_hi-1;   // stay in segment
                    buf[u] = __builtin_nontemporal_load(pbase + (size_t)tn * 4);

                    const float P = fmaf(h0d2, sxc, p);      // L1 consumes h0_{t-2}
                    const float g = fmaf(h, s_h, P);
                    const float v = fmaf(Bc, fast_rcp(1.0f + exp2_(g)), Ac);
                    const float w = v * qperm<0xB1>(v);
                    const float cpn = fmaf(qperm<0xAA>(v), cp, qperm<0x00>(w));
                    const float th = fmaf(-2.0f, fast_rcp(1.0f + exp2_(cpn)), 1.0f);
                    const float hn = qperm<0xFF>(v) * th;
                    // first 2 steps of each segment: L1 redoes steps done by the
                    // previous segment's flush (or spin-up at t=0) -> discard.
                    const bool disc = (u < 2) && (t0 == t_lo) && L;
                    h  = disc ? h  : hn;
                    cp = disc ? cp : cpn;
                    h0d2 = h0d1;
                    h0d1 = rowshr4(h);                       // L0 h -> L1 quad (DPP)
                    if (L && t >= t_lo + 2)
                        st_wt(obase + (size_t)(t-2) * BB, h);
                }
            }

            const float h0f = h, c0f = cp;       // L0 finals (flush skips L0)

            // flush: 2 L1-only steps so rows [t_hi-2, t_hi) publish this segment
            #pragma unroll
            for (int fs = 0; fs < 2; ++fs) {
                const float p = L ? pcc : buf[0];
                const float P = fmaf(h0d2, sxc, p);
                const float g = fmaf(h, s_h, P);
                const float v = fmaf(Bc, fast_rcp(1.0f + exp2_(g)), Ac);
                const float w = v * qperm<0xB1>(v);
                const float cpn = fmaf(qperm<0xAA>(v), cp, qperm<0x00>(w));
                const float th = fmaf(-2.0f, fast_rcp(1.0f + exp2_(cpn)), 1.0f);
                const float hn = qperm<0xFF>(v) * th;
                if (L) { h = hn; cp = cpn;
                         st_wt(obase + (size_t)(t_hi-2+fs) * BB, hn); }
                h0d2 = h0d1;
            }

            if (s == NSEG-1 && gate == 0) {
                if (L) { st_wt(finals + 128 + bb, h);
                         st_wt(finals + 384 + bb, cp  * (0.5f/L2E)); }
                else   { st_wt(finals + bb,       h0f);
                         st_wt(finals + 256 + bb, c0f * (0.5f/L2E)); }
            }

            asm volatile("s_waitcnt vmcnt(0)" ::: "memory");  // payload at IC
            if (lane == 0)
                __hip_atomic_fetch_add(&flags[SCFLAG(s)], 1, __ATOMIC_RELAXED, __HIP_MEMORY_SCOPE_AGENT);
        }
        return;
    }

    if (blk < NSCANB + NK1B) {
        // ---------------- k1 wave (2048 waves, seg-ordered sweep) ----------------
        const int i = (blk - NSCANB)*4 + wv;     // 0..2047
        float4 wvv[4][4];
        #pragma unroll
        for (int j = 0; j < 4; ++j)
            #pragma unroll
            for (int it = 0; it < 4; ++it)
                wvv[j][it] = *(const float4*)(W + j*DD + HH + it*256 + lane*4);
        const float4 b0 = *(const float4*)(bias);

        for (int s = 0; s < NSEG; ++s) {
            #pragma unroll 2
            for (int j = 0; j < 4; ++j) {
                const int row = s*ROWSEG + i*4 + j;
                const float* xr = x + (size_t)row * HH;
                float a0 = 0.f, a1 = 0.f, a2 = 0.f, a3 = 0.f;
                #pragma unroll
                for (int it = 0; it < 4; ++it) {
                    f32x4 xv = __builtin_nontemporal_load((const f32x4*)xr + it*64 + lane);
                    a0 = fmaf(xv.x, wvv[0][it].x, fmaf(xv.y, wvv[0][it].y, fmaf(xv.z, wvv[0][it].z, fmaf(xv.w, wvv[0][it].w, a0))));
                    a1 = fmaf(xv.x, wvv[1][it].x, fmaf(xv.y, wvv[1][it].y, fmaf(xv.z, wvv[1][it].z, fmaf(xv.w, wvv[1][it].w, a1))));
                    a2 = fmaf(xv.x, wvv[2][it].x, fmaf(xv.y, wvv[2][it].y, fmaf(xv.z, wvv[2][it].z, fmaf(xv.w, wvv[2][it].w, a2))));
                    a3 = fmaf(xv.x, wvv[3][it].x, fmaf(xv.y, wvv[3][it].y, fmaf(xv.z, wvv[3][it].z, fmaf(xv.w, wvv[3][it].w, a3))));
                }
                #pragma unroll
                for (int off = 32; off >= 1; off >>= 1) {
                    a0 += __shfl_xor(a0, off, 64);
                    a1 += __shfl_xor(a1, off, 64);
                    a2 += __shfl_xor(a2, off, 64);
                    a3 += __shfl_xor(a3, off, 64);
                }
                if (lane == 0) {
                    const int b = row & (BB-1), t = row >> 7;
                    f32x4 r = {(a0 + b0.x) * (-L2E),
                               (a1 + b0.y) * ( 2.0f * L2E),
                               (a2 + b0.z) * (-L2E),
                               (a3 + b0.w) * (-L2E)};
                    st_wt_x4(pre + (((size_t)b << 10) + t) * 4, r);
                }
            }
            asm volatile("s_waitcnt vmcnt(0)" ::: "memory");  // pre at IC
            if (lane == 0)
                __hip_atomic_fetch_add(&flags[K1FLAG(s, i & 7)], 1, __ATOMIC_RELAXED, __HIP_MEMORY_SCOPE_AGENT);
        }
        return;
    }

    // ---------------- k3 wave (2016 waves, chase scan) ----------------
    if (tid == 0) ready = 0;
    __syncthreads();
    const int u = (blk - NSCANB - NK1B)*4 + wv;  // 0..2015
    const int lbase = (u < 32) ? u*8 : 256 + (u-32)*4;  // 32*8 + 1984*4 = 8192
    const int cnt   = (u < 32) ? 8 : 4;
    for (int s = 0; s < NSEG; ++s) {
        // hierarchical wait: tid0 polls global flag, publishes to LDS
        if (tid == 0) {
            int guard = 0;
            while (__hip_atomic_load(&flags[SCFLAG(s)], __ATOMIC_RELAXED, __HIP_MEMORY_SCOPE_AGENT) < 16) {
                __builtin_amdgcn_s_sleep(32);
                if (++guard > (1<<19)) break;    // never hit legitimately
            }
            __hip_atomic_store(&ready, s+1, __ATOMIC_RELAXED, __HIP_MEMORY_SCOPE_WORKGROUP);
        }
        {
            int guard = 0;
            while (__hip_atomic_load(&ready, __ATOMIC_RELAXED, __HIP_MEMORY_SCOPE_WORKGROUP) < s+1) {
                __builtin_amdgcn_s_sleep(4);
                if (++guard > (1<<22)) break;    // never hit legitimately
            }
            asm volatile("" ::: "memory");       // no payload-load hoisting
        }
        const int r0 = s*ROWSEG + lbase;
        for (int q = 0; q < cnt; q += 4) {
            f32x4 v4 = __builtin_nontemporal_load((const f32x4*)(s_out + r0 + q));
            #pragma unroll
            for (int jj = 0; jj < 4; ++jj) {
                const float vb = (jj==0) ? v4.x : (jj==1) ? v4.y : (jj==2) ? v4.z : v4.w;
                const f32x4 vv = {vb, vb, vb, vb};
                f32x4* dst = (f32x4*)(out + (size_t)(r0 + q + jj) * HH);
                #pragma unroll
                for (int it = 0; it < 4; ++it)
                    __builtin_nontemporal_store(vv, dst + it*64 + lane);
            }
        }
    }
    if (u < 512) {
        // finals rows: safe to overwrite pre region (scan fully done)
        const float v = __builtin_nontemporal_load(finals + u);
        const f32x4 vv = {v, v, v, v};
        f32x4* dst = (f32x4*)(out + (size_t)(NROWS + u) * HH);
        #pragma unroll
        for (int it = 0; it < 4; ++it)
            __builtin_nontemporal_store(vv, dst + it*64 + lane);
    }
}

extern "C" void kernel_launch(void* const* d_in, const int* in_sizes, int n_in,
                              void* d_out, int out_size, void* d_ws, size_t ws_size,
                              hipStream_t stream) {
    const float* x    = (const float*)d_in[0];   // [S,B,H]
    const float* W    = (const float*)d_in[1];   // [L,4,D]
    const float* bias = (const float*)d_in[2];   // [L,4]
    float* out = (float*)d_out;

    float* s_out  = (float*)d_ws;                // [131072]
    float* finals = s_out + NROWS;               // [512]
    int*   flags  = (int*)(finals + 512);        // [4608] ints

    hipMemsetAsync(flags, 0, FLAG_INTS * sizeof(int), stream);
    hipLaunchKernelGGL(lstm_df, dim3(NBLK), dim3(256), 0, stream,
                       x, W, bias, out, s_out, finals, flags);
}

// Round 7
// 247.270 us; speedup vs baseline: 1.3588x; 1.1297x over previous
//
#include <hip/hip_runtime.h>

#define SS 1024
#define BB 128
#define HH 1024
#define DD 2048
#define NROWS (SS*BB)            // 131072 (t,b) rows
#define NSEG 16
#define TSEG 64                  // segment = 64 timesteps
#define ROWSEG (TSEG*BB)         // 8192 rows per segment
#define NSCANB 4                 // blocks 0..3 -> 16 scan waves
#define NK1B   512               // 2048 k1 waves (read x -> pre), seg-ordered
#define NK3B   504               // 2016 k3 waves (s_out -> out broadcast)
#define NBLK   (NSCANB+NK1B+NK3B)  // 1020 blocks <= 4/CU x 256CU -> co-resident
#define K1WAVES 2048
#define L2E  1.4426950408889634f

// flags layout (ints, 128B-strided):
//   k1done shard: flags[(seg*8+shard)*32], target 256 each (8 shards = 2048 waves)
//   scandone:     flags[4096 + seg*32],    target 16
#define K1FLAG(s,sh) (((s)*8 + (sh))*32)
#define SCFLAG(s)    (4096 + (s)*32)
#define FLAG_INTS    4608

typedef float f32x4 __attribute__((ext_vector_type(4)));

__device__ __forceinline__ float fast_rcp(float x)  { return __builtin_amdgcn_rcpf(x); }
__device__ __forceinline__ float exp2_(float x)     { return __builtin_amdgcn_exp2f(x); }

// Write-through stores (sc0 sc1): payload lands at the device coherence
// point, no dirty L2 copy. NOT tracked by the compiler's vmcnt bookkeeping
// -- so the scan loop must contain no compiler-inserted load-waits (R17's
// 279us: per-step waits silently drained store ACKs, ~650cy/step).
__device__ __forceinline__ void st_wt(float* p, float v){
    asm volatile("global_store_dword %0, %1, off sc0 sc1" :: "v"(p), "v"(v));
}
__device__ __forceinline__ void st_wt_x4(float* p, f32x4 v){
    asm volatile("global_store_dwordx4 %0, %1, off sc0 sc1" :: "v"(p), "v"(v));
}

template<int CTRL>
__device__ __forceinline__ float qperm(float x){
    return __int_as_float(__builtin_amdgcn_update_dpp(0, __float_as_int(x), CTRL, 0xF, 0xF, true));
}
__device__ __forceinline__ float rowshr4(float x){
    return __int_as_float(__builtin_amdgcn_update_dpp(0, __float_as_int(x), 0x114, 0xF, 0xF, true));
}

// R18: zero-memory-op scan inner loop.
//  pre layout  [b][seg][gate][ts] : scan lane's 64 values contiguous ->
//    16 asm dwordx4 loads + ONE vmcnt(0) per segment (no stores outstanding
//    at that point -> no pollution), then 64 pure-VALU unrolled steps.
//  s_out layout [b][t] : scan batches h in a rolling 4-reg window, one
//    st_wt_x4 per 4 steps from 1 lane; stores only drained by the
//    end-of-segment vmcnt(0) the flag publish needs anyway.
__global__ __launch_bounds__(256, 4) void lstm_df(
    const float* __restrict__ x, const float* __restrict__ W,
    const float* __restrict__ bias, float* out,
    float* __restrict__ s_out, float* __restrict__ finals,
    int* __restrict__ flags)
{
    __shared__ int ready;                    // k3 blocks: highest segment+1 ready
    float* pre = out + (size_t)NROWS * HH;   // hT/cT rows (2 MB) as pre scratch
    const int tid  = threadIdx.x;
    const int lane = tid & 63;
    const int wv   = tid >> 6;
    const int blk  = blockIdx.x;

    if (blk < NSCANB) {
        // ---------------- scan wave (16 waves, 8 batches each) ----------------
        const int sw   = blk*4 + wv;          // 0..15
        const int gate = lane & 3;
        const int L    = (lane >> 2) & 1;
        const int lb   = lane >> 3;
        const int bb   = sw*8 + lb;

        // 12 weight sums computed in-register
        float sh = 0.f, sx = 0.f;
        for (int q = 0; q < 12; ++q) {
            const int base = (q < 4) ? q*DD
                           : (q < 8) ? 4*DD + (q-4)*DD
                                     : 4*DD + (q-8)*DD + HH;
            float v = 0.f;
            #pragma unroll
            for (int k = 0; k < 16; ++k) v += W[base + lane + k*64];
            #pragma unroll
            for (int off = 32; off >= 1; off >>= 1) v += __shfl_xor(v, off, 64);
            if (q == L*4 + gate) sh = v;
            if (q == 8 + gate)   sx = v;
        }
        const float sc  = (gate == 1) ? (2.0f*L2E) : (-L2E);
        const float s_h = sh * sc;
        const float sxc = L ? sx * sc : 0.0f;
        const float pcc = L ? bias[4+gate] * sc : 0.0f;
        const float Ac  = (gate == 1) ? 1.0f : 0.0f;
        const float Bc  = (gate == 0) ? (2.0f*L2E) : ((gate == 1) ? -2.0f : 1.0f);

        const float* pcol = pre + ((size_t)bb << 12) + gate*TSEG;  // + s*256 + ts
        float* so = s_out + (size_t)bb * SS;                        // + t

        float h = 0.f, cp = 0.f, h0d1 = 0.f, h0d2 = 0.f;           // persistent
        float hb0 = 0.f, hb1 = 0.f, hb2 = 0.f, hb3 = 0.f;          // h batch (slot=t&3)

        for (int s = 0; s < NSEG; ++s) {
            // wait k1(s): sum of 8 shards == 2048
            {
                int guard = 0;
                for (;;) {
                    int tot = 0;
                    #pragma unroll
                    for (int i = 0; i < 8; ++i)
                        tot += __hip_atomic_load(&flags[K1FLAG(s,i)], __ATOMIC_RELAXED, __HIP_MEMORY_SCOPE_AGENT);
                    if (tot >= K1WAVES) break;
                    __builtin_amdgcn_s_sleep(8);
                    if (++guard > (1<<20)) break;   // never hit legitimately
                }
                asm volatile("" ::: "memory");      // no payload-load hoisting
            }
            const int t_lo = s*TSEG, t_hi = t_lo + TSEG;

            // load the lane's full segment column (64 floats, contiguous)
            const float* pb = pcol + s*256;
            f32x4 sv[16];
            #pragma unroll
            for (int q = 0; q < 16; ++q)
                asm volatile("global_load_dwordx4 %0, %1, off offset:%2"
                             : "=v"(sv[q]) : "v"(pb), "i"(q*16));
            asm volatile("s_waitcnt vmcnt(0)" ::: "memory");
            __builtin_amdgcn_sched_barrier(0);      // rule #18: pin VALU after wait

            #pragma unroll
            for (int u = 0; u < TSEG; ++u) {
                const float p = L ? pcc : sv[u>>2][u&3];

                const float P = fmaf(h0d2, sxc, p);      // L1 consumes h0_{t-2}
                const float g = fmaf(h, s_h, P);
                const float v = fmaf(Bc, fast_rcp(1.0f + exp2_(g)), Ac);
                const float w = v * qperm<0xB1>(v);
                const float cpn = fmaf(qperm<0xAA>(v), cp, qperm<0x00>(w));
                const float th = fmaf(-2.0f, fast_rcp(1.0f + exp2_(cpn)), 1.0f);
                const float hn = qperm<0xFF>(v) * th;
                // first 2 steps of each segment: L1 redoes steps done by the
                // previous segment's flush (or spin-up at t=0) -> discard.
                const bool disc = (u < 2) && L;
                h  = disc ? h  : hn;
                cp = disc ? cp : cpn;
                h0d2 = h0d1;
                h0d1 = rowshr4(h);                       // L0 h -> L1 quad (DPP)

                // L1's h at loop-u is h1 for row tau = t_lo+u-2; slot = tau&3
                if (((u+2)&3)==0) hb0 = h;
                else if (((u+2)&3)==1) hb1 = h;
                else if (((u+2)&3)==2) hb2 = h;
                else hb3 = h;
                // store batch of 4 rows (tau-3..tau) once slot 3 filled;
                // skip u==1 (covers previous segment, already written)
                if ((u&3)==1 && u>=5 && L && gate==0) {
                    f32x4 hv = {hb0,hb1,hb2,hb3};
                    st_wt_x4(so + t_lo + u - 5, hv);
                }
            }

            const float h0f = h, c0f = cp;       // L0 finals (flush skips L0)

            // flush: 2 L1-only steps -> rows [t_hi-2, t_hi); slots 2,3 then store
            #pragma unroll
            for (int fs = 0; fs < 2; ++fs) {
                const float p = L ? pcc : sv[0][0];  // L0 value unused (disc)
                const float P = fmaf(h0d2, sxc, p);
                const float g = fmaf(h, s_h, P);
                const float v = fmaf(Bc, fast_rcp(1.0f + exp2_(g)), Ac);
                const float w = v * qperm<0xB1>(v);
                const float cpn = fmaf(qperm<0xAA>(v), cp, qperm<0x00>(w));
                const float th = fmaf(-2.0f, fast_rcp(1.0f + exp2_(cpn)), 1.0f);
                const float hn = qperm<0xFF>(v) * th;
                if (L) { h = hn; cp = cpn;
                         if (fs == 0) hb2 = hn; else hb3 = hn; }
                h0d2 = h0d1;
            }
            if (L && gate == 0) {
                f32x4 hv = {hb0,hb1,hb2,hb3};
                st_wt_x4(so + t_hi - 4, hv);
            }

            if (s == NSEG-1 && gate == 0) {
                if (L) { st_wt(finals + 128 + bb, h);
                         st_wt(finals + 384 + bb, cp  * (0.5f/L2E)); }
                else   { st_wt(finals + bb,       h0f);
                         st_wt(finals + 256 + bb, c0f * (0.5f/L2E)); }
            }

            asm volatile("s_waitcnt vmcnt(0)" ::: "memory");  // payload at IC
            if (lane == 0)
                __hip_atomic_fetch_add(&flags[SCFLAG(s)], 1, __ATOMIC_RELAXED, __HIP_MEMORY_SCOPE_AGENT);
        }
        return;
    }

    if (blk < NSCANB + NK1B) {
        // ---------------- k1 wave (2048 waves, seg-ordered sweep) ----------------
        const int i = (blk - NSCANB)*4 + wv;     // 0..2047
        float4 wvv[4][4];
        #pragma unroll
        for (int j = 0; j < 4; ++j)
            #pragma unroll
            for (int it = 0; it < 4; ++it)
                wvv[j][it] = *(const float4*)(W + j*DD + HH + it*256 + lane*4);
        const float4 b0 = *(const float4*)(bias);

        for (int s = 0; s < NSEG; ++s) {
            #pragma unroll 2
            for (int j = 0; j < 4; ++j) {
                const int row = s*ROWSEG + i*4 + j;
                const float* xr = x + (size_t)row * HH;
                float a0 = 0.f, a1 = 0.f, a2 = 0.f, a3 = 0.f;
                #pragma unroll
                for (int it = 0; it < 4; ++it) {
                    f32x4 xv = __builtin_nontemporal_load((const f32x4*)xr + it*64 + lane);
                    a0 = fmaf(xv.x, wvv[0][it].x, fmaf(xv.y, wvv[0][it].y, fmaf(xv.z, wvv[0][it].z, fmaf(xv.w, wvv[0][it].w, a0))));
                    a1 = fmaf(xv.x, wvv[1][it].x, fmaf(xv.y, wvv[1][it].y, fmaf(xv.z, wvv[1][it].z, fmaf(xv.w, wvv[1][it].w, a1))));
                    a2 = fmaf(xv.x, wvv[2][it].x, fmaf(xv.y, wvv[2][it].y, fmaf(xv.z, wvv[2][it].z, fmaf(xv.w, wvv[2][it].w, a2))));
                    a3 = fmaf(xv.x, wvv[3][it].x, fmaf(xv.y, wvv[3][it].y, fmaf(xv.z, wvv[3][it].z, fmaf(xv.w, wvv[3][it].w, a3))));
                }
                #pragma unroll
                for (int off = 32; off >= 1; off >>= 1) {
                    a0 += __shfl_xor(a0, off, 64);
                    a1 += __shfl_xor(a1, off, 64);
                    a2 += __shfl_xor(a2, off, 64);
                    a3 += __shfl_xor(a3, off, 64);
                }
                // transposed pre write: lanes 0..3 each store one gate
                if (lane < 4) {
                    const int b = row & (BB-1), t = row >> 7;
                    const float g0 = (a0 + b0.x) * (-L2E);
                    const float g1 = (a1 + b0.y) * ( 2.0f * L2E);
                    const float g2 = (a2 + b0.z) * (-L2E);
                    const float g3 = (a3 + b0.w) * (-L2E);
                    const float mv = (lane==0) ? g0 : (lane==1) ? g1 : (lane==2) ? g2 : g3;
                    st_wt(pre + ((size_t)b << 12) + s*256 + lane*TSEG + (t & (TSEG-1)), mv);
                }
            }
            asm volatile("s_waitcnt vmcnt(0)" ::: "memory");  // pre at IC
            if (lane == 0)
                __hip_atomic_fetch_add(&flags[K1FLAG(s, i & 7)], 1, __ATOMIC_RELAXED, __HIP_MEMORY_SCOPE_AGENT);
        }
        return;
    }

    // ---------------- k3 wave (2016 waves, chase scan) ----------------
    if (tid == 0) ready = 0;
    __syncthreads();
    const int u = (blk - NSCANB - NK1B)*4 + wv;  // 0..2015
    const int nrep = (u < 32) ? 2 : 1;           // 2016+32 = 2048 groups of 4 t's
    for (int s = 0; s < NSEG; ++s) {
        // hierarchical wait: tid0 polls global flag, publishes to LDS
        if (tid == 0) {
            int guard = 0;
            while (__hip_atomic_load(&flags[SCFLAG(s)], __ATOMIC_RELAXED, __HIP_MEMORY_SCOPE_AGENT) < 16) {
                __builtin_amdgcn_s_sleep(32);
                if (++guard > (1<<19)) break;    // never hit legitimately
            }
            __hip_atomic_store(&ready, s+1, __ATOMIC_RELAXED, __HIP_MEMORY_SCOPE_WORKGROUP);
        }
        {
            int guard = 0;
            while (__hip_atomic_load(&ready, __ATOMIC_RELAXED, __HIP_MEMORY_SCOPE_WORKGROUP) < s+1) {
                __builtin_amdgcn_s_sleep(4);
                if (++guard > (1<<22)) break;    // never hit legitimately
            }
            asm volatile("" ::: "memory");       // no payload-load hoisting
        }
        for (int rep = 0; rep < nrep; ++rep) {
            const int g  = rep ? (2016 + u) : u;     // group: 4 consecutive t, one b
            const int b  = g >> 4;
            const int t0 = s*TSEG + (g & 15)*4;
            f32x4 v4 = __builtin_nontemporal_load((const f32x4*)(s_out + (size_t)b*SS + t0));
            #pragma unroll
            for (int jj = 0; jj < 4; ++jj) {
                const float vb = (jj==0) ? v4.x : (jj==1) ? v4.y : (jj==2) ? v4.z : v4.w;
                const f32x4 vv = {vb, vb, vb, vb};
                f32x4* dst = (f32x4*)(out + ((size_t)(t0+jj)*BB + b) * HH);
                #pragma unroll
                for (int it = 0; it < 4; ++it)
                    __builtin_nontemporal_store(vv, dst + it*64 + lane);
            }
        }
    }
    if (u < 512) {
        // finals rows: safe to overwrite pre region (scan fully done)
        const float v = __builtin_nontemporal_load(finals + u);
        const f32x4 vv = {v, v, v, v};
        f32x4* dst = (f32x4*)(out + (size_t)(NROWS + u) * HH);
        #pragma unroll
        for (int it = 0; it < 4; ++it)
            __builtin_nontemporal_store(vv, dst + it*64 + lane);
    }
}

extern "C" void kernel_launch(void* const* d_in, const int* in_sizes, int n_in,
                              void* d_out, int out_size, void* d_ws, size_t ws_size,
                              hipStream_t stream) {
    const float* x    = (const float*)d_in[0];   // [S,B,H]
    const float* W    = (const float*)d_in[1];   // [L,4,D]
    const float* bias = (const float*)d_in[2];   // [L,4]
    float* out = (float*)d_out;

    float* s_out  = (float*)d_ws;                // [131072]
    float* finals = s_out + NROWS;               // [512]
    int*   flags  = (int*)(finals + 512);        // [4608] ints

    hipMemsetAsync(flags, 0, FLAG_INTS * sizeof(int), stream);
    hipLaunchKernelGGL(lstm_df, dim3(NBLK), dim3(256), 0, stream,
                       x, W, bias, out, s_out, finals, flags);
}